// Round 1
// baseline (400.068 us; speedup 1.0000x reference)
//
#include <hip/hip_runtime.h>
#include <hip/hip_bf16.h>

#define NROWS 8192
#define DDIM 256
#define CORRF (256.0f / 255.0f)
#define BT 128
#define BK 32
#define LSTR 40   // padded LDS row stride in bf16 elements (80 B, 16B-aligned, 2-way bank alias = free)

using bf16x8 = __attribute__((ext_vector_type(8))) __bf16;
using f32x4  = __attribute__((ext_vector_type(4))) float;

__device__ inline unsigned short f2bf(float f) {
    // round-to-nearest-even bf16 (matches __float2bfloat16 for normal values)
    unsigned int b = __float_as_uint(f);
    unsigned int r = b + 0x7fffu + ((b >> 16) & 1u);
    return (unsigned short)(r >> 16);
}

// Kernel 1: one wave per row. L2-normalize, store bf16 e, per-row stats, reg term.
__global__ __launch_bounds__(256) void rowstats_kernel(
    const float* __restrict__ x, unsigned short* __restrict__ ebf,
    float* __restrict__ s_arr, float* __restrict__ m_arr,
    float* __restrict__ iv_arr, float* __restrict__ accums)
{
    int wave = threadIdx.x >> 6;
    int lane = threadIdx.x & 63;
    int row  = blockIdx.x * 4 + wave;

    const float4 v = reinterpret_cast<const float4*>(x + (size_t)row * DDIM)[lane];
    float ss = v.x * v.x + v.y * v.y + v.z * v.z + v.w * v.w;
    float sm = v.x + v.y + v.z + v.w;
    #pragma unroll
    for (int off = 32; off >= 1; off >>= 1) {
        ss += __shfl_xor(ss, off);
        sm += __shfl_xor(sm, off);
    }
    float invn = 1.0f / sqrtf(ss);

    ushort4 o;
    o.x = f2bf(v.x * invn);
    o.y = f2bf(v.y * invn);
    o.z = f2bf(v.z * invn);
    o.w = f2bf(v.w * invn);
    reinterpret_cast<ushort4*>(ebf + (size_t)row * DDIM)[lane] = o;

    if (lane == 0) {
        float Se  = sm * invn;               // sum of normalized row
        float Se2 = ss * invn * invn;        // sum of squares (≈1)
        float m = Se * (1.0f / DDIM);
        float s = Se2 * (1.0f / DDIM);
        float rv = CORRF * (s - m * m);      // unbiased row variance
        s_arr[row] = s;
        m_arr[row] = m;
        iv_arr[row] = 1.0f / rv;
        atomicAdd(&accums[4], fabsf(Se));    // Σ_i |Σ_j e_ij|
    }
}

// Kernel 2: fused E·E^T GEMM (bf16 MFMA) + distmat epilogue + masked-relu reduction.
__global__ __launch_bounds__(256) void snr_gemm_kernel(
    const unsigned short* __restrict__ ebf,
    const float* __restrict__ s_arr, const float* __restrict__ m_arr,
    const float* __restrict__ iv_arr, const int* __restrict__ labels,
    float* __restrict__ accums)
{
    __shared__ __align__(16) unsigned short As[BT * LSTR];
    __shared__ __align__(16) unsigned short Bs[BT * LSTR];
    __shared__ float sSi[BT], sMi[BT], sVi[BT], sSj[BT], sMj[BT];
    __shared__ int   sLi[BT], sLj[BT];
    __shared__ float redbuf[4][4];

    int tid  = threadIdx.x;
    int lane = tid & 63;
    int wave = tid >> 6;
    int wr = (wave >> 1) * 64;   // wave row offset in tile
    int wc = (wave & 1) * 64;    // wave col offset in tile
    int rowBase = blockIdx.y * BT;
    int colBase = blockIdx.x * BT;

    f32x4 acc[4][4];
    #pragma unroll
    for (int a = 0; a < 4; ++a)
        #pragma unroll
        for (int b = 0; b < 4; ++b)
            acc[a][b] = (f32x4){0.f, 0.f, 0.f, 0.f};

    int ldRow = tid >> 2;         // 0..63
    int ldKo  = (tid & 3) * 8;    // 0,8,16,24 (bf16 elems; 16B chunks)

    int mrow = lane & 15;
    int kq   = (lane >> 4) * 8;

    for (int k0 = 0; k0 < DDIM; k0 += BK) {
        #pragma unroll
        for (int p = 0; p < 2; ++p) {
            int r = ldRow + p * 64;
            uint4 av = *reinterpret_cast<const uint4*>(ebf + (size_t)(rowBase + r) * DDIM + k0 + ldKo);
            uint4 bv = *reinterpret_cast<const uint4*>(ebf + (size_t)(colBase + r) * DDIM + k0 + ldKo);
            *reinterpret_cast<uint4*>(&As[r * LSTR + ldKo]) = av;
            *reinterpret_cast<uint4*>(&Bs[r * LSTR + ldKo]) = bv;
        }
        __syncthreads();

        bf16x8 aF[4], bF[4];
        #pragma unroll
        for (int t = 0; t < 4; ++t) {
            aF[t] = *reinterpret_cast<const bf16x8*>(&As[(wr + t * 16 + mrow) * LSTR + kq]);
            bF[t] = *reinterpret_cast<const bf16x8*>(&Bs[(wc + t * 16 + mrow) * LSTR + kq]);
        }
        #pragma unroll
        for (int ti = 0; ti < 4; ++ti)
            #pragma unroll
            for (int tj = 0; tj < 4; ++tj)
                acc[ti][tj] = __builtin_amdgcn_mfma_f32_16x16x32_bf16(aF[ti], bF[tj], acc[ti][tj], 0, 0, 0);
        __syncthreads();
    }

    // Stage per-row / per-col stats into LDS
    if (tid < BT) {
        int gi = rowBase + tid;
        sSi[tid] = s_arr[gi]; sMi[tid] = m_arr[gi]; sVi[tid] = iv_arr[gi]; sLi[tid] = labels[gi];
    } else {
        int t = tid - BT;
        int gj = colBase + t;
        sSj[t] = s_arr[gj]; sMj[t] = m_arr[gj]; sLj[t] = labels[gj];
    }
    __syncthreads();

    // Epilogue: distmat + masked relu accumulation
    float ps = 0.f, ns = 0.f, pc = 0.f, nc = 0.f;
    int subr = (lane >> 4) * 4;
    int cj   = lane & 15;
    #pragma unroll
    for (int ti = 0; ti < 4; ++ti) {
        #pragma unroll
        for (int tj = 0; tj < 4; ++tj) {
            #pragma unroll
            for (int r = 0; r < 4; ++r) {
                int li = wr + ti * 16 + subr + r;            // C layout: row = quad*4 + reg
                int lj = wc + tj * 16 + cj;                  // col = lane&15
                float g  = acc[ti][tj][r] * (1.0f / 256.0f);
                float dm = sMi[li] - sMj[lj];
                float dist = CORRF * (sSi[li] + sSj[lj] - 2.0f * g - dm * dm) * sVi[li];
                bool same = (sLi[li] == sLj[lj]);
                int gi = rowBase + li, gj = colBase + lj;
                if (same) {
                    if (gi != gj) {
                        float pv = dist - 0.01f;
                        if (pv > 0.f) { ps += pv; pc += 1.f; }
                    }
                } else {
                    float nv = 0.2f - dist;
                    if (nv > 0.f) { ns += nv; nc += 1.f; }
                }
            }
        }
    }

    #pragma unroll
    for (int off = 32; off >= 1; off >>= 1) {
        ps += __shfl_down(ps, off);
        ns += __shfl_down(ns, off);
        pc += __shfl_down(pc, off);
        nc += __shfl_down(nc, off);
    }
    if (lane == 0) {
        redbuf[wave][0] = ps; redbuf[wave][1] = ns;
        redbuf[wave][2] = pc; redbuf[wave][3] = nc;
    }
    __syncthreads();
    if (tid == 0) {
        float a0 = 0, a1 = 0, a2 = 0, a3 = 0;
        #pragma unroll
        for (int w = 0; w < 4; ++w) {
            a0 += redbuf[w][0]; a1 += redbuf[w][1];
            a2 += redbuf[w][2]; a3 += redbuf[w][3];
        }
        atomicAdd(&accums[0], a0);
        atomicAdd(&accums[1], a1);
        atomicAdd(&accums[2], a2);
        atomicAdd(&accums[3], a3);
    }
}

__global__ void finalize_kernel(const float* __restrict__ accums, float* __restrict__ out) {
    float pos = accums[0] / (accums[2] + 1e-12f);
    float neg = accums[1] / (accums[3] + 1e-12f);
    out[0] = pos + neg + accums[4] * (0.1f / (float)NROWS);
}

extern "C" void kernel_launch(void* const* d_in, const int* in_sizes, int n_in,
                              void* d_out, int out_size, void* d_ws, size_t ws_size,
                              hipStream_t stream) {
    const float* embeds = (const float*)d_in[0];
    const int*   labels = (const int*)d_in[1];
    float* out = (float*)d_out;

    char* ws = (char*)d_ws;
    unsigned short* ebf = (unsigned short*)ws;                       // 8192*256*2 = 4 MB
    float* s_arr  = (float*)(ws + (size_t)NROWS * DDIM * 2);         // 32 KB
    float* m_arr  = s_arr + NROWS;
    float* iv_arr = m_arr + NROWS;
    float* accums = iv_arr + NROWS;                                  // [pos_s, neg_s, pos_c, neg_c, reg_s]

    hipMemsetAsync(accums, 0, 5 * sizeof(float), stream);

    rowstats_kernel<<<NROWS / 4, 256, 0, stream>>>(embeds, ebf, s_arr, m_arr, iv_arr, accums);

    dim3 grid(NROWS / BT, NROWS / BT);
    snr_gemm_kernel<<<grid, 256, 0, stream>>>(ebf, s_arr, m_arr, iv_arr, labels, accums);

    finalize_kernel<<<1, 1, 0, stream>>>(accums, out);
}

// Round 2
// 146.989 us; speedup vs baseline: 2.7218x; 2.7218x over previous
//
#include <hip/hip_runtime.h>
#include <hip/hip_bf16.h>

#define NROWS 8192
#define DDIM 256
#define CORRF (256.0f / 255.0f)
#define BT 128
#define BK 32
#define LSTR 40   // padded LDS row stride in bf16 elems (2-way bank alias only = free per m136)
#define NBLK ((NROWS / BT) * (NROWS / BT))   // 4096 gemm blocks

using bf16x8 = __attribute__((ext_vector_type(8))) __bf16;
using f32x4  = __attribute__((ext_vector_type(4))) float;

__device__ inline unsigned short f2bf(float f) {
    unsigned int b = __float_as_uint(f);
    unsigned int r = b + 0x7fffu + ((b >> 16) & 1u);
    return (unsigned short)(r >> 16);
}

// Kernel 1: one wave per row. Normalize, emit bf16 e, per-row epilogue constants.
// dist(i,j) = 1 + a_i*(b_j - 2*g_ij) + d_i*(2*m_j)   [derived: CORRF*iv_i*(s_i-m_i^2)=1]
__global__ __launch_bounds__(256) void rowstats_kernel(
    const float* __restrict__ x, unsigned short* __restrict__ ebf,
    float* __restrict__ aA, float* __restrict__ dA,
    float* __restrict__ bA, float* __restrict__ m2A,
    float* __restrict__ rabs)
{
    int wave = threadIdx.x >> 6;
    int lane = threadIdx.x & 63;
    int row  = blockIdx.x * 4 + wave;

    const float4 v = reinterpret_cast<const float4*>(x + (size_t)row * DDIM)[lane];
    float ss = v.x * v.x + v.y * v.y + v.z * v.z + v.w * v.w;
    float sm = v.x + v.y + v.z + v.w;
    #pragma unroll
    for (int off = 32; off >= 1; off >>= 1) {
        ss += __shfl_xor(ss, off);
        sm += __shfl_xor(sm, off);
    }
    float invn = 1.0f / sqrtf(ss);

    ushort4 o;
    o.x = f2bf(v.x * invn);
    o.y = f2bf(v.y * invn);
    o.z = f2bf(v.z * invn);
    o.w = f2bf(v.w * invn);
    reinterpret_cast<ushort4*>(ebf + (size_t)row * DDIM)[lane] = o;

    if (lane == 0) {
        float Se  = sm * invn;            // sum of normalized row
        float Se2 = ss * invn * invn;     // = 1 (sum of squares)
        float m = Se * (1.0f / DDIM);
        float s = Se2 * (1.0f / DDIM);
        float b = s - m * m;              // s_i - m_i^2
        float a = 1.0f / b;               // CORRF * (1/row_var)
        aA[row]  = a;
        dA[row]  = a * m;
        bA[row]  = b;
        m2A[row] = 2.0f * m;
        rabs[row] = fabsf(Se);
    }
}

// Kernel 2: fused E.E^T bf16 MFMA GEMM + distmat epilogue, per-block partials (no atomics).
__global__ __launch_bounds__(256) void snr_gemm_kernel(
    const unsigned short* __restrict__ ebf,
    const float* __restrict__ aA, const float* __restrict__ dA,
    const float* __restrict__ bA, const float* __restrict__ m2A,
    const int* __restrict__ labels,
    float* __restrict__ partials)
{
    __shared__ __align__(16) unsigned short As[BT * LSTR];
    __shared__ __align__(16) unsigned short Bs[BT * LSTR];
    __shared__ float sAi[BT], sDi[BT], sBj[BT], sM2j[BT];
    __shared__ int   sLi[BT], sLj[BT];
    __shared__ float redbuf[4][4];

    int tid  = threadIdx.x;
    int lane = tid & 63;
    int wave = tid >> 6;
    int wr = (wave >> 1) * 64;
    int wc = (wave & 1) * 64;
    int rowBase = blockIdx.y * BT;
    int colBase = blockIdx.x * BT;

    // Stage per-row/per-col epilogue constants (covered by K-loop's first barrier)
    if (tid < BT) {
        int gi = rowBase + tid;
        sAi[tid] = aA[gi]; sDi[tid] = dA[gi]; sLi[tid] = labels[gi];
    } else {
        int t = tid - BT;
        int gj = colBase + t;
        sBj[t] = bA[gj]; sM2j[t] = m2A[gj]; sLj[t] = labels[gj];
    }

    f32x4 acc[4][4];
    #pragma unroll
    for (int a = 0; a < 4; ++a)
        #pragma unroll
        for (int b = 0; b < 4; ++b)
            acc[a][b] = (f32x4){0.f, 0.f, 0.f, 0.f};

    int ldRow = tid >> 2;
    int ldKo  = (tid & 3) * 8;
    int mrow = lane & 15;
    int kq   = (lane >> 4) * 8;

    for (int k0 = 0; k0 < DDIM; k0 += BK) {
        #pragma unroll
        for (int p = 0; p < 2; ++p) {
            int r = ldRow + p * 64;
            uint4 av = *reinterpret_cast<const uint4*>(ebf + (size_t)(rowBase + r) * DDIM + k0 + ldKo);
            uint4 bv = *reinterpret_cast<const uint4*>(ebf + (size_t)(colBase + r) * DDIM + k0 + ldKo);
            *reinterpret_cast<uint4*>(&As[r * LSTR + ldKo]) = av;
            *reinterpret_cast<uint4*>(&Bs[r * LSTR + ldKo]) = bv;
        }
        __syncthreads();

        bf16x8 aF[4], bF[4];
        #pragma unroll
        for (int t = 0; t < 4; ++t) {
            aF[t] = *reinterpret_cast<const bf16x8*>(&As[(wr + t * 16 + mrow) * LSTR + kq]);
            bF[t] = *reinterpret_cast<const bf16x8*>(&Bs[(wc + t * 16 + mrow) * LSTR + kq]);
        }
        #pragma unroll
        for (int ti = 0; ti < 4; ++ti)
            #pragma unroll
            for (int tj = 0; tj < 4; ++tj)
                acc[ti][tj] = __builtin_amdgcn_mfma_f32_16x16x32_bf16(aF[ti], bF[tj], acc[ti][tj], 0, 0, 0);
        __syncthreads();
    }

    // Epilogue. acc holds raw e_i.e_j (x256 of g). g2 = acc/128 = 2*g.
    float ps = 0.f, ns = 0.f, pc = 0.f, nc = 0.f;
    int subr = (lane >> 4) * 4;
    int cj   = lane & 15;

    float bC[4], mC[4]; int LC[4], GJ[4];
    #pragma unroll
    for (int tj = 0; tj < 4; ++tj) {
        int lj = wc + tj * 16 + cj;
        bC[tj] = sBj[lj]; mC[tj] = sM2j[lj]; LC[tj] = sLj[lj];
        GJ[tj] = colBase + lj;
    }

    #pragma unroll
    for (int ti = 0; ti < 4; ++ti) {
        #pragma unroll
        for (int r = 0; r < 4; ++r) {
            int li = wr + ti * 16 + subr + r;
            float ai = sAi[li], di = sDi[li];
            int   Li = sLi[li];
            int   gi = rowBase + li;
            #pragma unroll
            for (int tj = 0; tj < 4; ++tj) {
                float g2 = acc[ti][tj][r] * (1.0f / 128.0f);
                float dist = fmaf(ai, bC[tj] - g2, fmaf(di, mC[tj], 1.0f));
                bool same = (Li == LC[tj]);
                float pv = dist - 0.01f;
                float nv = 0.2f - dist;
                bool posok = same && (gi != GJ[tj]) && (pv > 0.f);
                bool negok = (!same) && (nv > 0.f);
                ps += posok ? pv : 0.f;
                pc += posok ? 1.f : 0.f;
                ns += negok ? nv : 0.f;
                nc += negok ? 1.f : 0.f;
            }
        }
    }

    #pragma unroll
    for (int off = 32; off >= 1; off >>= 1) {
        ps += __shfl_down(ps, off);
        ns += __shfl_down(ns, off);
        pc += __shfl_down(pc, off);
        nc += __shfl_down(nc, off);
    }
    if (lane == 0) {
        redbuf[wave][0] = ps; redbuf[wave][1] = ns;
        redbuf[wave][2] = pc; redbuf[wave][3] = nc;
    }
    __syncthreads();
    if (tid < 4) {
        float v = redbuf[0][tid] + redbuf[1][tid] + redbuf[2][tid] + redbuf[3][tid];
        int bid = blockIdx.y * gridDim.x + blockIdx.x;
        partials[bid * 4 + tid] = v;
    }
}

// Kernel 3: reduce per-block partials + per-row reg terms, emit scalar loss.
__global__ __launch_bounds__(256) void finalize_kernel(
    const float* __restrict__ partials, const float* __restrict__ rabs,
    float* __restrict__ out)
{
    int tid = threadIdx.x;
    float s0 = 0, s1 = 0, s2 = 0, s3 = 0, rr = 0;
    for (int i = tid; i < NBLK; i += 256) {
        float4 p = reinterpret_cast<const float4*>(partials)[i];
        s0 += p.x; s1 += p.y; s2 += p.z; s3 += p.w;
    }
    for (int i = tid; i < NROWS; i += 256) rr += rabs[i];

    #pragma unroll
    for (int off = 32; off >= 1; off >>= 1) {
        s0 += __shfl_down(s0, off);
        s1 += __shfl_down(s1, off);
        s2 += __shfl_down(s2, off);
        s3 += __shfl_down(s3, off);
        rr += __shfl_down(rr, off);
    }
    __shared__ float red[4][5];
    int wave = tid >> 6, lane = tid & 63;
    if (lane == 0) {
        red[wave][0] = s0; red[wave][1] = s1; red[wave][2] = s2;
        red[wave][3] = s3; red[wave][4] = rr;
    }
    __syncthreads();
    if (tid == 0) {
        float a0 = 0, a1 = 0, a2 = 0, a3 = 0, a4 = 0;
        #pragma unroll
        for (int w = 0; w < 4; ++w) {
            a0 += red[w][0]; a1 += red[w][1]; a2 += red[w][2];
            a3 += red[w][3]; a4 += red[w][4];
        }
        float pos = a0 / (a2 + 1e-12f);
        float neg = a1 / (a3 + 1e-12f);
        out[0] = pos + neg + a4 * (0.1f / (float)NROWS);
    }
}

extern "C" void kernel_launch(void* const* d_in, const int* in_sizes, int n_in,
                              void* d_out, int out_size, void* d_ws, size_t ws_size,
                              hipStream_t stream) {
    const float* embeds = (const float*)d_in[0];
    const int*   labels = (const int*)d_in[1];
    float* out = (float*)d_out;

    char* ws = (char*)d_ws;
    unsigned short* ebf = (unsigned short*)ws;              // 4 MB
    float* aA   = (float*)(ws + (size_t)NROWS * DDIM * 2);  // 32 KB each
    float* dA   = aA + NROWS;
    float* bA   = dA + NROWS;
    float* m2A  = bA + NROWS;
    float* rabs = m2A + NROWS;
    float* partials = rabs + NROWS;                         // 4096*4 floats = 64 KB

    rowstats_kernel<<<NROWS / 4, 256, 0, stream>>>(embeds, ebf, aA, dA, bA, m2A, rabs);

    dim3 grid(NROWS / BT, NROWS / BT);
    snr_gemm_kernel<<<grid, 256, 0, stream>>>(ebf, aA, dA, bA, m2A, labels, partials);

    finalize_kernel<<<1, 256, 0, stream>>>(partials, rabs, out);
}

// Round 3
// 127.173 us; speedup vs baseline: 3.1459x; 1.1558x over previous
//
#include <hip/hip_runtime.h>
#include <hip/hip_bf16.h>

#define NROWS 8192
#define DDIM 256
#define BT 128
#define BK 64
#define GT (NROWS / BT)            // 64 tile-rows
#define NBT (GT * (GT + 1) / 2)    // 2080 upper-triangle blocks

using bf16x8 = __attribute__((ext_vector_type(8))) __bf16;
using f32x4  = __attribute__((ext_vector_type(4))) float;

__device__ __forceinline__ void glds16(const unsigned short* g, unsigned short* l) {
    // async global->LDS DMA, 16B/lane; LDS dest = wave-uniform base + lane*16
    __builtin_amdgcn_global_load_lds(
        (const __attribute__((address_space(1))) unsigned int*)g,
        (__attribute__((address_space(3))) unsigned int*)l,
        16, 0, 0);
}

__device__ __forceinline__ unsigned short f2bf(float f) {
    unsigned int b = __float_as_uint(f);
    unsigned int r = b + 0x7fffu + ((b >> 16) & 1u);
    return (unsigned short)(r >> 16);
}

// Kernel 1: one wave per row. Normalize, emit bf16 e, per-row epilogue constants.
// dist(i,j) = 1 + a_i*(b_j - 2*g_ij) + d_i*(2*m_j)   [uses CORRF*iv_i*(s_i-m_i^2)=1]
__global__ __launch_bounds__(256) void rowstats_kernel(
    const float* __restrict__ x, unsigned short* __restrict__ ebf,
    float* __restrict__ aA, float* __restrict__ dA,
    float* __restrict__ bA, float* __restrict__ m2A,
    float* __restrict__ rabs)
{
    int wave = threadIdx.x >> 6;
    int lane = threadIdx.x & 63;
    int row  = blockIdx.x * 4 + wave;

    const float4 v = reinterpret_cast<const float4*>(x + (size_t)row * DDIM)[lane];
    float ss = v.x * v.x + v.y * v.y + v.z * v.z + v.w * v.w;
    float sm = v.x + v.y + v.z + v.w;
    #pragma unroll
    for (int off = 32; off >= 1; off >>= 1) {
        ss += __shfl_xor(ss, off);
        sm += __shfl_xor(sm, off);
    }
    float invn = 1.0f / sqrtf(ss);

    ushort4 o;
    o.x = f2bf(v.x * invn);
    o.y = f2bf(v.y * invn);
    o.z = f2bf(v.z * invn);
    o.w = f2bf(v.w * invn);
    reinterpret_cast<ushort4*>(ebf + (size_t)row * DDIM)[lane] = o;

    if (lane == 0) {
        float Se  = sm * invn;
        float Se2 = ss * invn * invn;     // = 1
        float m = Se * (1.0f / DDIM);
        float s = Se2 * (1.0f / DDIM);
        float b = s - m * m;
        float a = 1.0f / b;
        aA[row]  = a;
        dA[row]  = a * m;
        bA[row]  = b;
        m2A[row] = 2.0f * m;
        rabs[row] = fabsf(Se);
    }
}

// Kernel 2: upper-triangle E.E^T bf16 MFMA GEMM (global_load_lds staging, XOR-swizzled LDS)
// + two-sided distmat epilogue, per-block partials.
__global__ __launch_bounds__(256) void snr_gemm_kernel(
    const unsigned short* __restrict__ ebf,
    const float* __restrict__ aA, const float* __restrict__ dA,
    const float* __restrict__ bA, const float* __restrict__ m2A,
    const int* __restrict__ labels,
    float* __restrict__ partials)
{
    __shared__ __align__(16) unsigned short As[BT * BK];   // 16 KB, swizzled chunks
    __shared__ __align__(16) unsigned short Bs[BT * BK];   // 16 KB
    __shared__ float sAi[BT], sDi[BT], sBi[BT], sM2i[BT];
    __shared__ float sAj[BT], sDj[BT], sBj[BT], sM2j[BT];
    __shared__ int   sLi[BT], sLj[BT];
    __shared__ float redbuf[4][4];

    int tid  = threadIdx.x;
    int lane = tid & 63;
    int wave = tid >> 6;
    int wr = (wave >> 1) * 64;
    int wc = (wave & 1) * 64;

    // decode triangular block id -> (bi, bj), bi <= bj
    int t = blockIdx.x;
    int bi = (int)((2.0f * GT + 1.0f
                    - sqrtf((2.0f * GT + 1.0f) * (2.0f * GT + 1.0f) - 8.0f * (float)t)) * 0.5f);
    while ((bi + 1) * GT - ((bi + 1) * bi) / 2 <= t) ++bi;
    while (bi * GT - (bi * (bi - 1)) / 2 > t) --bi;
    int bj = bi + (t - (bi * GT - (bi * (bi - 1)) / 2));
    int rowBase = bi * BT, colBase = bj * BT;
    bool diag = (bi == bj);

    // stage per-row / per-col epilogue constants (covered by first K-loop barrier)
    if (tid < BT) {
        int gi = rowBase + tid;
        sAi[tid] = aA[gi]; sDi[tid] = dA[gi]; sBi[tid] = bA[gi]; sM2i[tid] = m2A[gi];
        sLi[tid] = labels[gi];
    } else {
        int tt = tid - BT;
        int gj = colBase + tt;
        sAj[tt] = aA[gj]; sDj[tt] = dA[gj]; sBj[tt] = bA[gj]; sM2j[tt] = m2A[gj];
        sLj[tt] = labels[gj];
    }

    // staging addresses: chunk q = p*256+tid; logical (row=q>>3, slot=q&7),
    // slot holds k-chunk kc = slot ^ (row&7)  (XOR swizzle, conflict-free frag reads)
    const unsigned short* gA[4];
    const unsigned short* gB[4];
    unsigned short* lpA[4];
    unsigned short* lpB[4];
    #pragma unroll
    for (int p = 0; p < 4; ++p) {
        int q   = p * 256 + tid;
        int row = q >> 3;
        int kc  = (q & 7) ^ (row & 7);
        gA[p] = ebf + (size_t)(rowBase + row) * DDIM + kc * 8;
        gB[p] = ebf + (size_t)(colBase + row) * DDIM + kc * 8;
        lpA[p] = As + q * 8;
        lpB[p] = Bs + q * 8;
    }

    // fragment LDS offsets (elems), swizzle-aware
    int mrow = lane & 15;
    int kch  = lane >> 4;          // 16B k-chunk within half
    int offA[4][2], offB[4][2];
    #pragma unroll
    for (int t4 = 0; t4 < 4; ++t4) {
        int rA = wr + t4 * 16 + mrow;
        int rB = wc + t4 * 16 + mrow;
        #pragma unroll
        for (int h = 0; h < 2; ++h) {
            offA[t4][h] = (rA * 8 + ((h * 4 + kch) ^ (rA & 7))) * 8;
            offB[t4][h] = (rB * 8 + ((h * 4 + kch) ^ (rB & 7))) * 8;
        }
    }

    f32x4 acc[4][4];
    #pragma unroll
    for (int a = 0; a < 4; ++a)
        #pragma unroll
        for (int b = 0; b < 4; ++b)
            acc[a][b] = (f32x4){0.f, 0.f, 0.f, 0.f};

    for (int it = 0; it < 4; ++it) {
        #pragma unroll
        for (int p = 0; p < 4; ++p) {
            glds16(gA[p], lpA[p]);
            glds16(gB[p], lpB[p]);
            gA[p] += BK;
            gB[p] += BK;
        }
        asm volatile("s_waitcnt vmcnt(0)" ::: "memory");
        __syncthreads();

        #pragma unroll
        for (int h = 0; h < 2; ++h) {
            bf16x8 aF[4], bF[4];
            #pragma unroll
            for (int t4 = 0; t4 < 4; ++t4) {
                aF[t4] = *reinterpret_cast<const bf16x8*>(As + offA[t4][h]);
                bF[t4] = *reinterpret_cast<const bf16x8*>(Bs + offB[t4][h]);
            }
            #pragma unroll
            for (int ti = 0; ti < 4; ++ti)
                #pragma unroll
                for (int tj = 0; tj < 4; ++tj)
                    acc[ti][tj] = __builtin_amdgcn_mfma_f32_16x16x32_bf16(aF[ti], bF[tj], acc[ti][tj], 0, 0, 0);
        }
        __syncthreads();
    }

    // Epilogue: acc = raw e_i.e_j = 256*g. g2 = acc/128 = 2g.
    float ps = 0.f, ns = 0.f;
    unsigned int pcw = 0, ncw = 0;   // wave-uniform counts via ballot/popc (SALU)
    int subr = (lane >> 4) * 4;
    int cj   = lane & 15;

    float bCj[4], mCj[4], aCj[4], dCj[4];
    int LCj[4];
    #pragma unroll
    for (int tj = 0; tj < 4; ++tj) {
        int lj = wc + tj * 16 + cj;
        bCj[tj] = sBj[lj]; mCj[tj] = sM2j[lj];
        aCj[tj] = sAj[lj]; dCj[tj] = sDj[lj];
        LCj[tj] = sLj[lj];
    }

    if (!diag) {
        #pragma unroll
        for (int ti = 0; ti < 4; ++ti) {
            #pragma unroll
            for (int r = 0; r < 4; ++r) {
                int li = wr + ti * 16 + subr + r;
                float aR = sAi[li], dR = sDi[li], bR = sBi[li], m2R = sM2i[li];
                int LR = sLi[li];
                #pragma unroll
                for (int tj = 0; tj < 4; ++tj) {
                    float g2 = acc[ti][tj][r] * (1.0f / 128.0f);
                    bool same = (LR == LCj[tj]);
                    float dij = fmaf(aR, bCj[tj] - g2, fmaf(dR, mCj[tj], 1.0f));
                    float dji = fmaf(aCj[tj], bR - g2, fmaf(dCj[tj], m2R, 1.0f));
                    float v1 = same ? (dij - 0.01f) : (0.2f - dij);
                    float v2 = same ? (dji - 0.01f) : (0.2f - dji);
                    bool p1 = same && (v1 > 0.f);
                    bool p2 = same && (v2 > 0.f);
                    bool n1 = (!same) && (v1 > 0.f);
                    bool n2 = (!same) && (v2 > 0.f);
                    ps += (p1 ? v1 : 0.f) + (p2 ? v2 : 0.f);
                    ns += (n1 ? v1 : 0.f) + (n2 ? v2 : 0.f);
                    pcw += (unsigned)__popcll(__ballot(p1)) + (unsigned)__popcll(__ballot(p2));
                    ncw += (unsigned)__popcll(__ballot(n1)) + (unsigned)__popcll(__ballot(n2));
                }
            }
        }
    } else {
        #pragma unroll
        for (int ti = 0; ti < 4; ++ti) {
            #pragma unroll
            for (int r = 0; r < 4; ++r) {
                int li = wr + ti * 16 + subr + r;
                float aR = sAi[li], dR = sDi[li];
                int LR = sLi[li];
                #pragma unroll
                for (int tj = 0; tj < 4; ++tj) {
                    int lj = wc + tj * 16 + cj;
                    float g2 = acc[ti][tj][r] * (1.0f / 128.0f);
                    bool same = (LR == LCj[tj]);
                    float dij = fmaf(aR, bCj[tj] - g2, fmaf(dR, mCj[tj], 1.0f));
                    float v1 = same ? (dij - 0.01f) : (0.2f - dij);
                    bool p1 = same && (li != lj) && (v1 > 0.f);
                    bool n1 = (!same) && (v1 > 0.f);
                    ps += p1 ? v1 : 0.f;
                    ns += n1 ? v1 : 0.f;
                    pcw += (unsigned)__popcll(__ballot(p1));
                    ncw += (unsigned)__popcll(__ballot(n1));
                }
            }
        }
    }

    #pragma unroll
    for (int off = 32; off >= 1; off >>= 1) {
        ps += __shfl_down(ps, off);
        ns += __shfl_down(ns, off);
    }
    if (lane == 0) {
        redbuf[wave][0] = ps; redbuf[wave][1] = ns;
        redbuf[wave][2] = (float)pcw; redbuf[wave][3] = (float)ncw;
    }
    __syncthreads();
    if (tid < 4) {
        float v = redbuf[0][tid] + redbuf[1][tid] + redbuf[2][tid] + redbuf[3][tid];
        partials[blockIdx.x * 4 + tid] = v;
    }
}

// Kernel 3: reduce per-block partials + per-row reg terms, emit scalar loss.
__global__ __launch_bounds__(256) void finalize_kernel(
    const float* __restrict__ partials, const float* __restrict__ rabs,
    float* __restrict__ out)
{
    int tid = threadIdx.x;
    float s0 = 0, s1 = 0, s2 = 0, s3 = 0, rr = 0;
    for (int i = tid; i < NBT; i += 256) {
        float4 p = reinterpret_cast<const float4*>(partials)[i];
        s0 += p.x; s1 += p.y; s2 += p.z; s3 += p.w;
    }
    for (int i = tid; i < NROWS; i += 256) rr += rabs[i];

    #pragma unroll
    for (int off = 32; off >= 1; off >>= 1) {
        s0 += __shfl_down(s0, off);
        s1 += __shfl_down(s1, off);
        s2 += __shfl_down(s2, off);
        s3 += __shfl_down(s3, off);
        rr += __shfl_down(rr, off);
    }
    __shared__ float red[4][5];
    int wave = tid >> 6, lane = tid & 63;
    if (lane == 0) {
        red[wave][0] = s0; red[wave][1] = s1; red[wave][2] = s2;
        red[wave][3] = s3; red[wave][4] = rr;
    }
    __syncthreads();
    if (tid == 0) {
        float a0 = 0, a1 = 0, a2 = 0, a3 = 0, a4 = 0;
        #pragma unroll
        for (int w = 0; w < 4; ++w) {
            a0 += red[w][0]; a1 += red[w][1]; a2 += red[w][2];
            a3 += red[w][3]; a4 += red[w][4];
        }
        float pos = a0 / (a2 + 1e-12f);
        float neg = a1 / (a3 + 1e-12f);
        out[0] = pos + neg + a4 * (0.1f / (float)NROWS);
    }
}

extern "C" void kernel_launch(void* const* d_in, const int* in_sizes, int n_in,
                              void* d_out, int out_size, void* d_ws, size_t ws_size,
                              hipStream_t stream) {
    const float* embeds = (const float*)d_in[0];
    const int*   labels = (const int*)d_in[1];
    float* out = (float*)d_out;

    char* ws = (char*)d_ws;
    unsigned short* ebf = (unsigned short*)ws;              // 4 MB
    float* aA   = (float*)(ws + (size_t)NROWS * DDIM * 2);
    float* dA   = aA + NROWS;
    float* bA   = dA + NROWS;
    float* m2A  = bA + NROWS;
    float* rabs = m2A + NROWS;
    float* partials = rabs + NROWS;                         // NBT*4 floats

    rowstats_kernel<<<NROWS / 4, 256, 0, stream>>>(embeds, ebf, aA, dA, bA, m2A, rabs);

    snr_gemm_kernel<<<NBT, 256, 0, stream>>>(ebf, aA, dA, bA, m2A, labels, partials);

    finalize_kernel<<<1, 256, 0, stream>>>(partials, rabs, out);
}